// Round 5
// baseline (508.484 us; speedup 1.0000x reference)
//
#include <hip/hip_runtime.h>
#include <math.h>
#include <stdint.h>

#define D_MODEL 1024
#define NH      16
#define DK      64
#define BS      4
#define TS      2048
#define M_ROWS  (BS*TS)       // 8192
#define C3      (3*D_MODEL)   // 3072

typedef __attribute__((ext_vector_type(8))) short          short8;
typedef __attribute__((ext_vector_type(4))) float          f32x4;
typedef __attribute__((ext_vector_type(8))) __bf16         bf16x8;
typedef __attribute__((ext_vector_type(4))) unsigned short ushort4_t;

// fp32 -> bf16 round-to-nearest-even
static __device__ __forceinline__ unsigned short f2bf(float f) {
    unsigned u = __builtin_bit_cast(unsigned, f);
    u += 0x7fffu + ((u >> 16) & 1u);
    return (unsigned short)(u >> 16);
}
static __device__ __forceinline__ float bf2f(unsigned short h) {
    unsigned u = ((unsigned)h) << 16;
    return __builtin_bit_cast(float, u);
}
static __device__ __forceinline__ f32x4 mfma16(short8 a, short8 b, f32x4 c) {
    return __builtin_amdgcn_mfma_f32_16x16x32_bf16(
        __builtin_bit_cast(bf16x8, a), __builtin_bit_cast(bf16x8, b), c, 0, 0, 0);
}
// async global->LDS, 16B per lane; LDS dest = wave-uniform base + lane*16
static __device__ __forceinline__ void gll16(const void* g, void* l) {
    __builtin_amdgcn_global_load_lds(
        (const __attribute__((address_space(1))) void*)g,
        (__attribute__((address_space(3))) void*)l, 16, 0, 0);
}

// ---------------------------------------------------------------------------
// cast_split: fp32 -> (bf16 hi, bf16 lo) elementwise. n4 = count/4.
// ---------------------------------------------------------------------------
__global__ __launch_bounds__(256)
void cast_split(const float* __restrict__ src, unsigned short* __restrict__ hi,
                unsigned short* __restrict__ lo, int n4) {
    int i = blockIdx.x * blockDim.x + threadIdx.x;
    const int stride = gridDim.x * blockDim.x;
    for (; i < n4; i += stride) {
        float4 v = reinterpret_cast<const float4*>(src)[i];
        float f0 = v.x, f1 = v.y, f2 = v.z, f3 = v.w;
        ushort4_t h, l;
        h[0] = f2bf(f0); l[0] = f2bf(f0 - bf2f(h[0]));
        h[1] = f2bf(f1); l[1] = f2bf(f1 - bf2f(h[1]));
        h[2] = f2bf(f2); l[2] = f2bf(f2 - bf2f(h[2]));
        h[3] = f2bf(f3); l[3] = f2bf(f3 - bf2f(h[3]));
        reinterpret_cast<ushort4_t*>(hi)[i] = h;
        reinterpret_cast<ushort4_t*>(lo)[i] = l;
    }
}

// ---------------------------------------------------------------------------
// cast_wT: W fp32 [K][N] -> Th, Tl bf16 [N][K] (transposed, k-contiguous).
// ---------------------------------------------------------------------------
__global__ __launch_bounds__(256)
void cast_wT(const float* __restrict__ W, unsigned short* __restrict__ Th,
             unsigned short* __restrict__ Tl, int K, int N) {
    __shared__ float Ls[32][36];
    const int tid = threadIdx.x;
    const int n0 = blockIdx.x * 32, k0 = blockIdx.y * 32;
    {
        const int row = tid >> 3, c4 = tid & 7;
        float4 v = *reinterpret_cast<const float4*>(&W[(size_t)(k0 + row) * N + n0 + c4 * 4]);
        *reinterpret_cast<float4*>(&Ls[row][c4 * 4]) = v;
    }
    __syncthreads();
    {
        const int nl = tid >> 3, c4 = tid & 7;
        ushort4_t h, l;
#pragma unroll
        for (int j = 0; j < 4; ++j) {
            float f = Ls[c4 * 4 + j][nl];
            h[j] = f2bf(f);
            l[j] = f2bf(f - bf2f(h[j]));
        }
        const size_t o = (size_t)(n0 + nl) * K + k0 + c4 * 4;
        *reinterpret_cast<ushort4_t*>(&Th[o]) = h;
        *reinterpret_cast<ushort4_t*>(&Tl[o]) = l;
    }
}

// ---------------------------------------------------------------------------
// v_transpose: qkv(h,l) V-columns -> Vt(h,l) [bh][dk=64][T] (key-contiguous).
// ---------------------------------------------------------------------------
__global__ __launch_bounds__(256)
void v_transpose(const unsigned short* __restrict__ qh, const unsigned short* __restrict__ ql,
                 unsigned short* __restrict__ vth, unsigned short* __restrict__ vtl) {
    __shared__ unsigned short Ls[64][68];
    const int tt = blockIdx.x, bh = blockIdx.y;
    const int b = bh >> 4, h = bh & 15;
    const size_t src_base = ((size_t)b * TS + (size_t)tt * 64) * C3 + 2 * D_MODEL + h * DK;
    const size_t dst_base = (size_t)bh * DK * TS + (size_t)tt * 64;
#pragma unroll
    for (int pass = 0; pass < 2; ++pass) {
        const unsigned short* src = pass ? ql : qh;
        unsigned short* dst = pass ? vtl : vth;
        if (pass) __syncthreads();
        for (int c = threadIdx.x; c < 1024; c += 256) {
            const int t = c >> 4, c4 = c & 15;
            ushort4_t v = *reinterpret_cast<const ushort4_t*>(&src[src_base + (size_t)t * C3 + c4 * 4]);
            *reinterpret_cast<ushort4_t*>(&Ls[t][c4 * 4]) = v;
        }
        __syncthreads();
        for (int c = threadIdx.x; c < 1024; c += 256) {
            const int d = c >> 4, t4 = c & 15;
            ushort4_t o;
            o[0] = Ls[t4 * 4 + 0][d];
            o[1] = Ls[t4 * 4 + 1][d];
            o[2] = Ls[t4 * 4 + 2][d];
            o[3] = Ls[t4 * 4 + 3][d];
            *reinterpret_cast<ushort4_t*>(&dst[dst_base + (size_t)d * TS + t4 * 4]) = o;
        }
    }
}

// ---------------------------------------------------------------------------
// gemm_split_8ph: C = (Ah+Al)@(Bh+Bl)^T + bias as a DENSE bf16 GEMM over
// virtual K' = 3K: virtual chunk (c,r) -> r=0: Ah.Bh, r=1: Ah.Bl, r=2: Al.Bh.
// Plane select lives in the global_load_lds SOURCE address; LDS/schedule are
// the dense 8-phase template's (T2+T3+T4+T5):
//   BM=256, BN=128, BK=64(virtual), 512 thr (8 waves, 4m x 2n), NT=3K/64.
//   3 LDS buffers (A 3x32KB + B 3x16KB = 144 KB) -> staging runs 2 tiles
//   ahead; vmcnt(6) once per tile (never 0 in-loop), published by barrier.
//   16B-slot XOR swizzle (slot ^= row&7) on stage-source and ds_read.
//   2 phases/tile: {ds_read || stage-issue; barrier; setprio(1) 16 MFMA; barrier}.
// Summation order identical to the 3-MFMA split loop -> bit-identical C.
// ---------------------------------------------------------------------------
template <int BF16OUT>
__global__ __launch_bounds__(512, 1)
void gemm_split_8ph(const unsigned short* __restrict__ Ah_g, const unsigned short* __restrict__ Al_g,
                    const unsigned short* __restrict__ Bh_g, const unsigned short* __restrict__ Bl_g,
                    const float* __restrict__ bias,
                    float* __restrict__ Cf, unsigned short* __restrict__ Ch,
                    unsigned short* __restrict__ Cl,
                    int M, int N, int K) {
    __shared__ unsigned short ALs[3][256 * 64];   // 96 KB
    __shared__ unsigned short BLs[3][128 * 64];   // 48 KB

    const int tid  = threadIdx.x;
    const int lane = tid & 63, wid = tid >> 6;    // 8 waves
    const int wm = wid >> 1, wn = wid & 1;        // 4 x 2
    const int bm = blockIdx.y * 256, bn = blockIdx.x * 128;
    const int lr = lane & 15, kg = lane >> 4;
    const int NT = (3 * K) / 64;                  // 48 for K=1024

    f32x4 acc[4][4];
#pragma unroll
    for (int m = 0; m < 4; ++m)
#pragma unroll
        for (int n = 0; n < 4; ++n) acc[m][n] = (f32x4){0.f, 0.f, 0.f, 0.f};

    // ---- staging: per-lane global source (plane+addr from virtual chunk),
    //      wave-uniform LDS dest (linear; HW adds lane*16) -------------------
    auto stageA = [&](int t) {
        const int b3 = t % 3;
#pragma unroll
        for (int half = 0; half < 2; ++half)
#pragma unroll
            for (int j = 0; j < 2; ++j) {
                const int L   = (wid * 2 + j) * 64 + lane;   // 16B slot 0..1023
                const int row = L >> 3, sl = L & 7;
                const int sv  = sl ^ (row & 7);              // virtual slot
                const int vc  = t * 2 + (sv >> 2);           // virtual chunk
                const int r3  = vc % 3;
                const int c   = vc / 3;
                const unsigned short* pl = (r3 == 2) ? Al_g : Ah_g;
                const size_t ga = (size_t)(bm + half * 128 + row) * K + c * 32 + (sv & 3) * 8;
                gll16(&pl[ga], &ALs[b3][half * 8192 + (wid * 2 + j) * 512]);
            }
    };
    auto stageB = [&](int t) {
        const int b3 = t % 3;
#pragma unroll
        for (int j = 0; j < 2; ++j) {
            const int L   = (wid * 2 + j) * 64 + lane;
            const int row = L >> 3, sl = L & 7;
            const int sv  = sl ^ (row & 7);
            const int vc  = t * 2 + (sv >> 2);
            const int r3  = vc % 3;
            const int c   = vc / 3;
            const unsigned short* pl = (r3 == 1) ? Bl_g : Bh_g;
            const size_t gb = (size_t)(bn + row) * K + c * 32 + (sv & 3) * 8;
            gll16(&pl[gb], &BLs[b3][(wid * 2 + j) * 512]);
        }
    };
    auto rdA = [&](int cur, int m, int kf) -> short8 {
        const int row = wm * 64 + m * 16 + lr;
        const int sp  = (kf * 4 + kg) ^ (row & 7);
        return *reinterpret_cast<const short8*>(&ALs[cur][row * 64 + sp * 8]);
    };
    auto rdB = [&](int cur, int n, int kf) -> short8 {
        const int row = wn * 64 + n * 16 + lr;
        const int sp  = (kf * 4 + kg) ^ (row & 7);
        return *reinterpret_cast<const short8*>(&BLs[cur][row * 64 + sp * 8]);
    };

    // prologue: tiles 0 and 1 in flight; drain tile 0 (6 left = tile 1's)
    stageA(0); stageB(0);
    stageA(1); stageB(1);
    asm volatile("s_waitcnt vmcnt(6)" ::: "memory");
    __builtin_amdgcn_s_barrier();

    for (int t = 0; t < NT; ++t) {
        const int cur = t % 3;
        // ---------------- phase 0: m-frags 0,1 ----------------
        short8 bfr[4][2];
#pragma unroll
        for (int n = 0; n < 4; ++n) {
            bfr[n][0] = rdB(cur, n, 0);
            bfr[n][1] = rdB(cur, n, 1);
        }
        short8 afr[2][2];
#pragma unroll
        for (int m = 0; m < 2; ++m) {
            afr[m][0] = rdA(cur, m, 0);
            afr[m][1] = rdA(cur, m, 1);
        }
        if (t + 2 < NT) stageA(t + 2);
        __builtin_amdgcn_s_barrier();
        __builtin_amdgcn_s_setprio(1);
#pragma unroll
        for (int m = 0; m < 2; ++m)
#pragma unroll
            for (int n = 0; n < 4; ++n) {
                acc[m][n] = mfma16(afr[m][0], bfr[n][0], acc[m][n]);
                acc[m][n] = mfma16(afr[m][1], bfr[n][1], acc[m][n]);
            }
        __builtin_amdgcn_s_setprio(0);
        __builtin_amdgcn_s_barrier();
        // ---------------- phase 1: m-frags 2,3 ----------------
#pragma unroll
        for (int m = 0; m < 2; ++m) {
            afr[m][0] = rdA(cur, m + 2, 0);
            afr[m][1] = rdA(cur, m + 2, 1);
        }
        if (t + 2 < NT) {
            stageB(t + 2);
            // queue: [t+1: 6][t+2: 6] -> drain t+1's, keep t+2's in flight
            asm volatile("s_waitcnt vmcnt(6)" ::: "memory");
        } else if (t + 1 < NT) {
            asm volatile("s_waitcnt vmcnt(0)" ::: "memory");
        }
        __builtin_amdgcn_s_barrier();
        __builtin_amdgcn_s_setprio(1);
#pragma unroll
        for (int m = 0; m < 2; ++m)
#pragma unroll
            for (int n = 0; n < 4; ++n) {
                acc[m + 2][n] = mfma16(afr[m][0], bfr[n][0], acc[m + 2][n]);
                acc[m + 2][n] = mfma16(afr[m][1], bfr[n][1], acc[m + 2][n]);
            }
        __builtin_amdgcn_s_setprio(0);
        __builtin_amdgcn_s_barrier();
    }

    // ---- epilogue: bias + store ------------------------------------------
    const int og = lane >> 4, oc = lane & 15;
#pragma unroll
    for (int n = 0; n < 4; ++n) {
        const int gc = bn + wn * 64 + n * 16 + oc;
        const float bz = bias[gc];
#pragma unroll
        for (int m = 0; m < 4; ++m) {
            const int gr0 = bm + wm * 64 + m * 16 + og * 4;
#pragma unroll
            for (int rr = 0; rr < 4; ++rr) {
                const float v = acc[m][n][rr] + bz;
                const size_t idx = (size_t)(gr0 + rr) * N + gc;
                if (BF16OUT) {
                    const unsigned short hh = f2bf(v);
                    Ch[idx] = hh;
                    Cl[idx] = f2bf(v - bf2f(hh));
                } else {
                    Cf[idx] = v;
                }
            }
        }
    }
}

// ---------------------------------------------------------------------------
// attn_mfma: causal flash attention (unchanged from round 4).
// 8 waves x 32 q-rows (512 thr), QBLK=256, block p does q-tiles {p, 7-p};
// K/V LDS-staged double-buffered via swizzled-source global_load_lds;
// swapped-operand QK^T (q lane-local -> 2-shfl softmax); setprio on MFMA.
// ---------------------------------------------------------------------------
__global__ __launch_bounds__(512, 2)
void attn_mfma(const unsigned short* __restrict__ qkvh,
               const unsigned short* __restrict__ vth, const unsigned short* __restrict__ vtl,
               unsigned short* __restrict__ yh, unsigned short* __restrict__ yl) {
    const int pr = blockIdx.x;                 // pair 0..3
    const int bh = blockIdx.y;                 // 0..63
    const int b = bh >> 4, h = bh & 15;
    const int tid = threadIdx.x, w = tid >> 6, lane = tid & 63;
    const int lr = lane & 15, lg = lane >> 4;

    __shared__ unsigned short Kt[2][64 * 64];
    __shared__ unsigned short Vhs[2][64 * 64];
    __shared__ unsigned short Vls[2][64 * 64];
    __shared__ unsigned short Ps[8][32 * 64];

    const size_t kbase  = (size_t)b * TS * C3 + D_MODEL + (size_t)h * DK;
    const size_t vbase  = (size_t)bh * DK * TS;
    const size_t qbase  = (size_t)b * TS * C3 + (size_t)h * DK;
    unsigned short* PsW = &Ps[w][0];

    const f32x4 fz = (f32x4){0.f, 0.f, 0.f, 0.f};

    const int srow = tid >> 3;
    const int ssc  = (tid & 7) ^ (srow & 7);
    const int slds = (w * 64) * 8;

    for (int qi = 0; qi < 2; ++qi) {
        const int qt = qi ? (7 - pr) : pr;
        const int q0 = qt * 256;
        const int qwbase = q0 + w * 32;

        short8 qreg[2][2];
#pragma unroll
        for (int mf = 0; mf < 2; ++mf) {
            const size_t qrow = qbase + (size_t)(qwbase + mf * 16 + lr) * C3;
            qreg[mf][0] = *reinterpret_cast<const short8*>(&qkvh[qrow + lg * 8]);
            qreg[mf][1] = *reinterpret_cast<const short8*>(&qkvh[qrow + 32 + lg * 8]);
        }

        f32x4 yacc[4][2];
#pragma unroll
        for (int df = 0; df < 4; ++df)
#pragma unroll
            for (int qf = 0; qf < 2; ++qf) yacc[df][qf] = fz;
        float mrun[2], lrun[2];
#pragma unroll
        for (int qf = 0; qf < 2; ++qf) { mrun[qf] = -1e30f; lrun[qf] = 0.f; }

        const int nkt = 4 * qt + 4;
        int cur = 0;

        auto stage = [&](int buf, int kt) {
            gll16(&qkvh[kbase + (size_t)(kt * 64 + srow) * C3 + ssc * 8], &Kt[buf][slds]);
            gll16(&vth[vbase + (size_t)srow * TS + kt * 64 + ssc * 8], &Vhs[buf][slds]);
            gll16(&vtl[vbase + (size_t)srow * TS + kt * 64 + ssc * 8], &Vls[buf][slds]);
        };
        auto ldsf = [&](const unsigned short* Tt, int row, int kslot) -> short8 {
            return *reinterpret_cast<const short8*>(
                reinterpret_cast<const char*>(Tt) + row * 128 + (((kslot ^ (row & 7)) & 7) << 4));
        };

        stage(cur, 0);
        for (int kt = 0; kt < nkt; ++kt) {
            __syncthreads();
            if (kt + 1 < nkt) stage(cur ^ 1, kt + 1);

            if (kt * 64 <= qwbase + 31) {
                f32x4 s[2][4];
                __builtin_amdgcn_s_setprio(1);
#pragma unroll
                for (int nf = 0; nf < 4; ++nf) {
                    const int krow = nf * 16 + lr;
                    short8 ka0 = ldsf(Kt[cur], krow, lg);
                    short8 ka1 = ldsf(Kt[cur], krow, 4 + lg);
#pragma unroll
                    for (int mf = 0; mf < 2; ++mf)
                        s[mf][nf] = mfma16(ka1, qreg[mf][1], mfma16(ka0, qreg[mf][0], fz));
                }
                __builtin_amdgcn_s_setprio(0);
#pragma unroll
                for (int mf = 0; mf < 2; ++mf)
#pragma unroll
                    for (int nf = 0; nf < 4; ++nf) s[mf][nf] *= 0.125f;
                if (kt * 64 + 63 > qwbase) {
#pragma unroll
                    for (int mf = 0; mf < 2; ++mf) {
                        const int q = qwbase + mf * 16 + lr;
#pragma unroll
                        for (int nf = 0; nf < 4; ++nf)
#pragma unroll
                            for (int rr = 0; rr < 4; ++rr)
                                if (kt * 64 + nf * 16 + lg * 4 + rr > q) s[mf][nf][rr] = -1e30f;
                    }
                }
                float sclv[2];
#pragma unroll
                for (int mf = 0; mf < 2; ++mf) {
                    float rm = s[mf][0][0];
#pragma unroll
                    for (int nf = 0; nf < 4; ++nf)
#pragma unroll
                        for (int rr = 0; rr < 4; ++rr) rm = fmaxf(rm, s[mf][nf][rr]);
                    rm = fmaxf(rm, __shfl_xor(rm, 16, 64));
                    rm = fmaxf(rm, __shfl_xor(rm, 32, 64));
                    const float mn = fmaxf(mrun[mf], rm);
                    float rs = 0.f;
#pragma unroll
                    for (int nf = 0; nf < 4; ++nf)
#pragma unroll
                        for (int rr = 0; rr < 4; ++rr) {
                            const float p = __expf(s[mf][nf][rr] - mn);
                            s[mf][nf][rr] = p;
                            rs += p;
                        }
                    rs += __shfl_xor(rs, 16, 64);
                    rs += __shfl_xor(rs, 32, 64);
                    sclv[mf] = __expf(mrun[mf] - mn);
                    lrun[mf] = lrun[mf] * sclv[mf] + rs;
                    mrun[mf] = mn;
                }
#pragma unroll
                for (int df = 0; df < 4; ++df)
#pragma unroll
                    for (int qf = 0; qf < 2; ++qf) yacc[df][qf] *= sclv[qf];
#pragma unroll
                for (int mf = 0; mf < 2; ++mf) {
                    const int q = mf * 16 + lr;
#pragma unroll
                    for (int nf = 0; nf < 4; ++nf) {
                        ushort4_t pw;
                        pw[0] = f2bf(s[mf][nf][0]);
                        pw[1] = f2bf(s[mf][nf][1]);
                        pw[2] = f2bf(s[mf][nf][2]);
                        pw[3] = f2bf(s[mf][nf][3]);
                        *reinterpret_cast<ushort4_t*>(
                            reinterpret_cast<char*>(PsW) +
                            ((q * 128 + (nf * 16 + lg * 4) * 2) ^ ((q & 7) << 4))) = pw;
                    }
                }
#pragma unroll
                for (int kf = 0; kf < 2; ++kf) {
                    short8 pb[2];
#pragma unroll
                    for (int qf = 0; qf < 2; ++qf) {
                        const int q = qf * 16 + lr;
                        pb[qf] = *reinterpret_cast<const short8*>(
                            reinterpret_cast<const char*>(PsW) +
                            q * 128 + ((((kf << 2) + lg) ^ (q & 7)) << 4));
                    }
                    __builtin_amdgcn_s_setprio(1);
#pragma unroll
                    for (int df = 0; df < 4; ++df) {
                        const int d = df * 16 + lr;
                        short8 va = ldsf(Vhs[cur], d, (kf << 2) + lg);
                        short8 vb = ldsf(Vls[cur], d, (kf << 2) + lg);
#pragma unroll
                        for (int qf = 0; qf < 2; ++qf) {
                            yacc[df][qf] = mfma16(va, pb[qf], yacc[df][qf]);
                            yacc[df][qf] = mfma16(vb, pb[qf], yacc[df][qf]);
                        }
                    }
                    __builtin_amdgcn_s_setprio(0);
                }
            }
            cur ^= 1;
        }

#pragma unroll
        for (int qf = 0; qf < 2; ++qf) {
            const float inv = 1.f / lrun[qf];
            const size_t ro = ((size_t)b * TS + (qwbase + qf * 16 + lr)) * D_MODEL + h * DK;
#pragma unroll
            for (int df = 0; df < 4; ++df) {
                ushort4_t oh, ol;
#pragma unroll
                for (int rr = 0; rr < 4; ++rr) {
                    const float v = yacc[df][qf][rr] * inv;
                    oh[rr] = f2bf(v);
                    ol[rr] = f2bf(v - bf2f(oh[rr]));
                }
                *reinterpret_cast<ushort4_t*>(&yh[ro + df * 16 + lg * 4]) = oh;
                *reinterpret_cast<ushort4_t*>(&yl[ro + df * 16 + lg * 4]) = ol;
            }
        }
    }
}

// ---------------------------------------------------------------------------
extern "C" void kernel_launch(void* const* d_in, const int* in_sizes, int n_in,
                              void* d_out, int out_size, void* d_ws, size_t ws_size,
                              hipStream_t stream) {
    const float* x      = (const float*)d_in[0];
    const float* W_qkv  = (const float*)d_in[1];
    const float* b_qkv  = (const float*)d_in[2];
    const float* W_proj = (const float*)d_in[3];
    const float* b_proj = (const float*)d_in[4];
    float* out = (float*)d_out;

    char* ws = (char*)d_ws;
    size_t off = 0;
    auto carve = [&](size_t elems) {
        unsigned short* p = (unsigned short*)(ws + off);
        off += elems * sizeof(unsigned short);
        return p;
    };
    unsigned short* xh   = carve((size_t)M_ROWS * D_MODEL);
    unsigned short* xl   = carve((size_t)M_ROWS * D_MODEL);
    unsigned short* wqh  = carve((size_t)C3 * D_MODEL);
    unsigned short* wql  = carve((size_t)C3 * D_MODEL);
    unsigned short* wph  = carve((size_t)D_MODEL * D_MODEL);
    unsigned short* wpl  = carve((size_t)D_MODEL * D_MODEL);
    unsigned short* qkvh = carve((size_t)M_ROWS * C3);
    unsigned short* qkvl = carve((size_t)M_ROWS * C3);
    unsigned short* vth  = carve((size_t)BS * NH * DK * TS);
    unsigned short* vtl  = carve((size_t)BS * NH * DK * TS);
    unsigned short* yhh  = carve((size_t)M_ROWS * D_MODEL);
    unsigned short* yll  = carve((size_t)M_ROWS * D_MODEL);

    cast_split<<<2048, 256, 0, stream>>>(x, xh, xl, M_ROWS * D_MODEL / 4);
    cast_wT<<<dim3(C3 / 32, D_MODEL / 32), 256, 0, stream>>>(W_qkv, wqh, wql, D_MODEL, C3);
    cast_wT<<<dim3(D_MODEL / 32, D_MODEL / 32), 256, 0, stream>>>(W_proj, wph, wpl, D_MODEL, D_MODEL);

    // qkv = x @ W_qkv + b_qkv  (8-phase, BM=256 BN=128, grid 24x32)
    gemm_split_8ph<1><<<dim3(C3 / 128, M_ROWS / 256), 512, 0, stream>>>(
        xh, xl, wqh, wql, b_qkv, nullptr, qkvh, qkvl, M_ROWS, C3, D_MODEL);

    v_transpose<<<dim3(TS / 64, BS * NH), 256, 0, stream>>>(qkvh, qkvl, vth, vtl);

    attn_mfma<<<dim3(4, BS * NH), 512, 0, stream>>>(qkvh, vth, vtl, yhh, yll);

    // out = y @ W_proj + b_proj  (8-phase, grid 8x32)
    gemm_split_8ph<0><<<dim3(D_MODEL / 128, M_ROWS / 256), 512, 0, stream>>>(
        yhh, yll, wph, wpl, b_proj, out, nullptr, nullptr, M_ROWS, D_MODEL, D_MODEL);
}

// Round 6
// 458.468 us; speedup vs baseline: 1.1091x; 1.1091x over previous
//
#include <hip/hip_runtime.h>
#include <math.h>
#include <stdint.h>

#define D_MODEL 1024
#define NH      16
#define DK      64
#define BS      4
#define TS      2048
#define M_ROWS  (BS*TS)       // 8192
#define C3      (3*D_MODEL)   // 3072

typedef __attribute__((ext_vector_type(8))) short          short8;
typedef __attribute__((ext_vector_type(4))) float          f32x4;
typedef __attribute__((ext_vector_type(8))) __bf16         bf16x8;
typedef __attribute__((ext_vector_type(4))) unsigned short ushort4_t;

// fp32 -> bf16 round-to-nearest-even
static __device__ __forceinline__ unsigned short f2bf(float f) {
    unsigned u = __builtin_bit_cast(unsigned, f);
    u += 0x7fffu + ((u >> 16) & 1u);
    return (unsigned short)(u >> 16);
}
static __device__ __forceinline__ float bf2f(unsigned short h) {
    unsigned u = ((unsigned)h) << 16;
    return __builtin_bit_cast(float, u);
}
static __device__ __forceinline__ f32x4 mfma16(short8 a, short8 b, f32x4 c) {
    return __builtin_amdgcn_mfma_f32_16x16x32_bf16(
        __builtin_bit_cast(bf16x8, a), __builtin_bit_cast(bf16x8, b), c, 0, 0, 0);
}
// async global->LDS, 16B per lane; LDS dest = wave-uniform base + lane*16
static __device__ __forceinline__ void gll16(const void* g, void* l) {
    __builtin_amdgcn_global_load_lds(
        (const __attribute__((address_space(1))) void*)g,
        (__attribute__((address_space(3))) void*)l, 16, 0, 0);
}

// ---------------------------------------------------------------------------
// cast_split: fp32 -> (bf16 hi, bf16 lo) elementwise. n4 = count/4.
// ---------------------------------------------------------------------------
__global__ __launch_bounds__(256)
void cast_split(const float* __restrict__ src, unsigned short* __restrict__ hi,
                unsigned short* __restrict__ lo, int n4) {
    int i = blockIdx.x * blockDim.x + threadIdx.x;
    const int stride = gridDim.x * blockDim.x;
    for (; i < n4; i += stride) {
        float4 v = reinterpret_cast<const float4*>(src)[i];
        float f0 = v.x, f1 = v.y, f2 = v.z, f3 = v.w;
        ushort4_t h, l;
        h[0] = f2bf(f0); l[0] = f2bf(f0 - bf2f(h[0]));
        h[1] = f2bf(f1); l[1] = f2bf(f1 - bf2f(h[1]));
        h[2] = f2bf(f2); l[2] = f2bf(f2 - bf2f(h[2]));
        h[3] = f2bf(f3); l[3] = f2bf(f3 - bf2f(h[3]));
        reinterpret_cast<ushort4_t*>(hi)[i] = h;
        reinterpret_cast<ushort4_t*>(lo)[i] = l;
    }
}

// ---------------------------------------------------------------------------
// cast_wT: W fp32 [K][N] -> Th, Tl bf16 [N][K] (transposed, k-contiguous).
// ---------------------------------------------------------------------------
__global__ __launch_bounds__(256)
void cast_wT(const float* __restrict__ W, unsigned short* __restrict__ Th,
             unsigned short* __restrict__ Tl, int K, int N) {
    __shared__ float Ls[32][36];
    const int tid = threadIdx.x;
    const int n0 = blockIdx.x * 32, k0 = blockIdx.y * 32;
    {
        const int row = tid >> 3, c4 = tid & 7;
        float4 v = *reinterpret_cast<const float4*>(&W[(size_t)(k0 + row) * N + n0 + c4 * 4]);
        *reinterpret_cast<float4*>(&Ls[row][c4 * 4]) = v;
    }
    __syncthreads();
    {
        const int nl = tid >> 3, c4 = tid & 7;
        ushort4_t h, l;
#pragma unroll
        for (int j = 0; j < 4; ++j) {
            float f = Ls[c4 * 4 + j][nl];
            h[j] = f2bf(f);
            l[j] = f2bf(f - bf2f(h[j]));
        }
        const size_t o = (size_t)(n0 + nl) * K + k0 + c4 * 4;
        *reinterpret_cast<ushort4_t*>(&Th[o]) = h;
        *reinterpret_cast<ushort4_t*>(&Tl[o]) = l;
    }
}

// ---------------------------------------------------------------------------
// v_transpose: qkv(h,l) V-columns -> Vt(h,l) [bh][dk=64][T] (key-contiguous).
// ---------------------------------------------------------------------------
__global__ __launch_bounds__(256)
void v_transpose(const unsigned short* __restrict__ qh, const unsigned short* __restrict__ ql,
                 unsigned short* __restrict__ vth, unsigned short* __restrict__ vtl) {
    __shared__ unsigned short Ls[64][68];
    const int tt = blockIdx.x, bh = blockIdx.y;
    const int b = bh >> 4, h = bh & 15;
    const size_t src_base = ((size_t)b * TS + (size_t)tt * 64) * C3 + 2 * D_MODEL + h * DK;
    const size_t dst_base = (size_t)bh * DK * TS + (size_t)tt * 64;
#pragma unroll
    for (int pass = 0; pass < 2; ++pass) {
        const unsigned short* src = pass ? ql : qh;
        unsigned short* dst = pass ? vtl : vth;
        if (pass) __syncthreads();
        for (int c = threadIdx.x; c < 1024; c += 256) {
            const int t = c >> 4, c4 = c & 15;
            ushort4_t v = *reinterpret_cast<const ushort4_t*>(&src[src_base + (size_t)t * C3 + c4 * 4]);
            *reinterpret_cast<ushort4_t*>(&Ls[t][c4 * 4]) = v;
        }
        __syncthreads();
        for (int c = threadIdx.x; c < 1024; c += 256) {
            const int d = c >> 4, t4 = c & 15;
            ushort4_t o;
            o[0] = Ls[t4 * 4 + 0][d];
            o[1] = Ls[t4 * 4 + 1][d];
            o[2] = Ls[t4 * 4 + 2][d];
            o[3] = Ls[t4 * 4 + 3][d];
            *reinterpret_cast<ushort4_t*>(&dst[dst_base + (size_t)d * TS + t4 * 4]) = o;
        }
    }
}

// ---------------------------------------------------------------------------
// gemm_split2: C = (Ah+Al)@(Bh+Bl)^T + bias, 3-MFMA split-bf16 (hh, hl, lh —
// same order/k-sequence as round-3 -> bit-identical output).
// ROUND 6 geometry: BM=256, BN=128, BK=32, 512 thr (8 waves, 4m x 2n),
// per-wave 64x64 (16 frags, 48 MFMA/tile). Each plane staged ONCE per tile
// (6 gll16/thread). LDS 96 KB double-buffered -> 1 block/CU, 2 waves/SIMD.
// One barrier per K-tile; stage(t+1) issued at tile top, drained by the
// tile-end __syncthreads ~1900 MFMA-cycles later (>> HBM latency).
// XOR-slot swizzle slot = kg ^ ((row>>1)&3) (round-3: 0 bank conflicts).
// Grids are exactly 256 blocks (zero tail): NTILE chained n-tiles per block;
// bid->(m,ng) mapping gives each XCD 4 A-panels (2 MB, L2-resident).
// ---------------------------------------------------------------------------
template <int BF16OUT, int NTILE>
__global__ __launch_bounds__(512, 1)
void gemm_split2(const unsigned short* __restrict__ Ah_g, const unsigned short* __restrict__ Al_g,
                 const unsigned short* __restrict__ Bh_g, const unsigned short* __restrict__ Bl_g,
                 const float* __restrict__ bias,
                 float* __restrict__ Cf, unsigned short* __restrict__ Ch,
                 unsigned short* __restrict__ Cl,
                 int M, int N, int K) {
    __shared__ unsigned short AhL[2][256 * 32];   // 32 KB
    __shared__ unsigned short AlL[2][256 * 32];   // 32 KB
    __shared__ unsigned short BhL[2][128 * 32];   // 16 KB
    __shared__ unsigned short BlL[2][128 * 32];   // 16 KB   total 96 KB

    const int tid  = threadIdx.x;
    const int lane = tid & 63, wid = tid >> 6;    // 8 waves
    const int wm = wid >> 1, wn = wid & 1;        // 4m x 2n -> 64x64 per wave
    const int lr = lane & 15, kg = lane >> 4;

    const int bid = blockIdx.x;                   // 0..255
    const int mb  = 4 * (bid & 7) + (bid >> 6);   // 0..31 (XCD-affine A panels)
    const int ng  = (bid >> 3) & 7;               // 0..7
    const int bm  = mb * 256;

    // staging geometry (16B slots; slot s of row r holds k-octet s^((r>>1)&3))
    const int arow0 = tid >> 2;                   // rows 0..127
    const int ao0   = (tid & 3) ^ ((arow0 >> 1) & 3);
    const int arow1 = arow0 + 128;                // rows 128..255
    const int ao1   = (tid & 3) ^ ((arow1 >> 1) & 3);
    const int brow  = tid >> 2;                   // rows 0..127
    const int bo    = (tid & 3) ^ ((brow >> 1) & 3);
    const int ldsw  = wid * 512;                  // wave-uniform base (shorts)

    for (int it = 0; it < NTILE; ++it) {
        const int bn = (ng * NTILE + it) * 128;

        f32x4 acc[4][4];
#pragma unroll
        for (int m = 0; m < 4; ++m)
#pragma unroll
            for (int n = 0; n < 4; ++n) acc[m][n] = (f32x4){0.f, 0.f, 0.f, 0.f};

        auto stage = [&](int buf, int k0) {
            gll16(&Ah_g[(size_t)(bm + arow0) * K + k0 + ao0 * 8], &AhL[buf][ldsw]);
            gll16(&Ah_g[(size_t)(bm + arow1) * K + k0 + ao1 * 8], &AhL[buf][4096 + ldsw]);
            gll16(&Al_g[(size_t)(bm + arow0) * K + k0 + ao0 * 8], &AlL[buf][ldsw]);
            gll16(&Al_g[(size_t)(bm + arow1) * K + k0 + ao1 * 8], &AlL[buf][4096 + ldsw]);
            gll16(&Bh_g[(size_t)(bn + brow) * K + k0 + bo * 8], &BhL[buf][ldsw]);
            gll16(&Bl_g[(size_t)(bn + brow) * K + k0 + bo * 8], &BlL[buf][ldsw]);
        };
        auto rd = [&](const unsigned short* P, int r) -> short8 {
            const int s = kg ^ ((r >> 1) & 3);
            return *reinterpret_cast<const short8*>(&P[r * 32 + s * 8]);
        };

        int cur = 0;
        stage(0, 0);
        __syncthreads();                          // tile 0 visible

        for (int t = 0; t < 32; ++t) {
            if (t + 1 < 32) stage(cur ^ 1, (t + 1) * 32);   // issue early

            short8 ah[4], al[4], bhf[4], blf[4];
#pragma unroll
            for (int m = 0; m < 4; ++m) {
                const int r = wm * 64 + m * 16 + lr;
                ah[m] = rd(&AhL[cur][0], r);
                al[m] = rd(&AlL[cur][0], r);
            }
#pragma unroll
            for (int n = 0; n < 4; ++n) {
                const int r = wn * 64 + n * 16 + lr;
                bhf[n] = rd(&BhL[cur][0], r);
                blf[n] = rd(&BlL[cur][0], r);
            }
            __builtin_amdgcn_s_setprio(1);
#pragma unroll
            for (int m = 0; m < 4; ++m)
#pragma unroll
                for (int n = 0; n < 4; ++n) {
                    acc[m][n] = mfma16(ah[m], bhf[n], acc[m][n]);
                    acc[m][n] = mfma16(ah[m], blf[n], acc[m][n]);
                    acc[m][n] = mfma16(al[m], bhf[n], acc[m][n]);
                }
            __builtin_amdgcn_s_setprio(0);
            __syncthreads();                      // drains vmcnt (late = cheap)
            cur ^= 1;
        }

        // ---- epilogue: bias + store --------------------------------------
        const int og = lane >> 4, oc = lane & 15;
#pragma unroll
        for (int n = 0; n < 4; ++n) {
            const int gc = bn + wn * 64 + n * 16 + oc;
            const float bz = bias[gc];
#pragma unroll
            for (int m = 0; m < 4; ++m) {
                const int gr0 = bm + wm * 64 + m * 16 + og * 4;
#pragma unroll
                for (int rr = 0; rr < 4; ++rr) {
                    const float v = acc[m][n][rr] + bz;
                    const size_t idx = (size_t)(gr0 + rr) * N + gc;
                    if (BF16OUT) {
                        const unsigned short hh = f2bf(v);
                        Ch[idx] = hh;
                        Cl[idx] = f2bf(v - bf2f(hh));
                    } else {
                        Cf[idx] = v;
                    }
                }
            }
        }
    }
}

// ---------------------------------------------------------------------------
// attn_mfma: causal flash attention (unchanged from round 4).
// 8 waves x 32 q-rows (512 thr), QBLK=256, block p does q-tiles {p, 7-p};
// K/V LDS-staged double-buffered via swizzled-source global_load_lds;
// swapped-operand QK^T (q lane-local -> 2-shfl softmax); setprio on MFMA.
// ---------------------------------------------------------------------------
__global__ __launch_bounds__(512, 2)
void attn_mfma(const unsigned short* __restrict__ qkvh,
               const unsigned short* __restrict__ vth, const unsigned short* __restrict__ vtl,
               unsigned short* __restrict__ yh, unsigned short* __restrict__ yl) {
    const int pr = blockIdx.x;                 // pair 0..3
    const int bh = blockIdx.y;                 // 0..63
    const int b = bh >> 4, h = bh & 15;
    const int tid = threadIdx.x, w = tid >> 6, lane = tid & 63;
    const int lr = lane & 15, lg = lane >> 4;

    __shared__ unsigned short Kt[2][64 * 64];
    __shared__ unsigned short Vhs[2][64 * 64];
    __shared__ unsigned short Vls[2][64 * 64];
    __shared__ unsigned short Ps[8][32 * 64];

    const size_t kbase  = (size_t)b * TS * C3 + D_MODEL + (size_t)h * DK;
    const size_t vbase  = (size_t)bh * DK * TS;
    const size_t qbase  = (size_t)b * TS * C3 + (size_t)h * DK;
    unsigned short* PsW = &Ps[w][0];

    const f32x4 fz = (f32x4){0.f, 0.f, 0.f, 0.f};

    const int srow = tid >> 3;
    const int ssc  = (tid & 7) ^ (srow & 7);
    const int slds = (w * 64) * 8;

    for (int qi = 0; qi < 2; ++qi) {
        const int qt = qi ? (7 - pr) : pr;
        const int q0 = qt * 256;
        const int qwbase = q0 + w * 32;

        short8 qreg[2][2];
#pragma unroll
        for (int mf = 0; mf < 2; ++mf) {
            const size_t qrow = qbase + (size_t)(qwbase + mf * 16 + lr) * C3;
            qreg[mf][0] = *reinterpret_cast<const short8*>(&qkvh[qrow + lg * 8]);
            qreg[mf][1] = *reinterpret_cast<const short8*>(&qkvh[qrow + 32 + lg * 8]);
        }

        f32x4 yacc[4][2];
#pragma unroll
        for (int df = 0; df < 4; ++df)
#pragma unroll
            for (int qf = 0; qf < 2; ++qf) yacc[df][qf] = fz;
        float mrun[2], lrun[2];
#pragma unroll
        for (int qf = 0; qf < 2; ++qf) { mrun[qf] = -1e30f; lrun[qf] = 0.f; }

        const int nkt = 4 * qt + 4;
        int cur = 0;

        auto stage = [&](int buf, int kt) {
            gll16(&qkvh[kbase + (size_t)(kt * 64 + srow) * C3 + ssc * 8], &Kt[buf][slds]);
            gll16(&vth[vbase + (size_t)srow * TS + kt * 64 + ssc * 8], &Vhs[buf][slds]);
            gll16(&vtl[vbase + (size_t)srow * TS + kt * 64 + ssc * 8], &Vls[buf][slds]);
        };
        auto ldsf = [&](const unsigned short* Tt, int row, int kslot) -> short8 {
            return *reinterpret_cast<const short8*>(
                reinterpret_cast<const char*>(Tt) + row * 128 + (((kslot ^ (row & 7)) & 7) << 4));
        };

        stage(cur, 0);
        for (int kt = 0; kt < nkt; ++kt) {
            __syncthreads();
            if (kt + 1 < nkt) stage(cur ^ 1, kt + 1);

            if (kt * 64 <= qwbase + 31) {
                f32x4 s[2][4];
                __builtin_amdgcn_s_setprio(1);
#pragma unroll
                for (int nf = 0; nf < 4; ++nf) {
                    const int krow = nf * 16 + lr;
                    short8 ka0 = ldsf(Kt[cur], krow, lg);
                    short8 ka1 = ldsf(Kt[cur], krow, 4 + lg);
#pragma unroll
                    for (int mf = 0; mf < 2; ++mf)
                        s[mf][nf] = mfma16(ka1, qreg[mf][1], mfma16(ka0, qreg[mf][0], fz));
                }
                __builtin_amdgcn_s_setprio(0);
#pragma unroll
                for (int mf = 0; mf < 2; ++mf)
#pragma unroll
                    for (int nf = 0; nf < 4; ++nf) s[mf][nf] *= 0.125f;
                if (kt * 64 + 63 > qwbase) {
#pragma unroll
                    for (int mf = 0; mf < 2; ++mf) {
                        const int q = qwbase + mf * 16 + lr;
#pragma unroll
                        for (int nf = 0; nf < 4; ++nf)
#pragma unroll
                            for (int rr = 0; rr < 4; ++rr)
                                if (kt * 64 + nf * 16 + lg * 4 + rr > q) s[mf][nf][rr] = -1e30f;
                    }
                }
                float sclv[2];
#pragma unroll
                for (int mf = 0; mf < 2; ++mf) {
                    float rm = s[mf][0][0];
#pragma unroll
                    for (int nf = 0; nf < 4; ++nf)
#pragma unroll
                        for (int rr = 0; rr < 4; ++rr) rm = fmaxf(rm, s[mf][nf][rr]);
                    rm = fmaxf(rm, __shfl_xor(rm, 16, 64));
                    rm = fmaxf(rm, __shfl_xor(rm, 32, 64));
                    const float mn = fmaxf(mrun[mf], rm);
                    float rs = 0.f;
#pragma unroll
                    for (int nf = 0; nf < 4; ++nf)
#pragma unroll
                        for (int rr = 0; rr < 4; ++rr) {
                            const float p = __expf(s[mf][nf][rr] - mn);
                            s[mf][nf][rr] = p;
                            rs += p;
                        }
                    rs += __shfl_xor(rs, 16, 64);
                    rs += __shfl_xor(rs, 32, 64);
                    sclv[mf] = __expf(mrun[mf] - mn);
                    lrun[mf] = lrun[mf] * sclv[mf] + rs;
                    mrun[mf] = mn;
                }
#pragma unroll
                for (int df = 0; df < 4; ++df)
#pragma unroll
                    for (int qf = 0; qf < 2; ++qf) yacc[df][qf] *= sclv[qf];
#pragma unroll
                for (int mf = 0; mf < 2; ++mf) {
                    const int q = mf * 16 + lr;
#pragma unroll
                    for (int nf = 0; nf < 4; ++nf) {
                        ushort4_t pw;
                        pw[0] = f2bf(s[mf][nf][0]);
                        pw[1] = f2bf(s[mf][nf][1]);
                        pw[2] = f2bf(s[mf][nf][2]);
                        pw[3] = f2bf(s[mf][nf][3]);
                        *reinterpret_cast<ushort4_t*>(
                            reinterpret_cast<char*>(PsW) +
                            ((q * 128 + (nf * 16 + lg * 4) * 2) ^ ((q & 7) << 4))) = pw;
                    }
                }
#pragma unroll
                for (int kf = 0; kf < 2; ++kf) {
                    short8 pb[2];
#pragma unroll
                    for (int qf = 0; qf < 2; ++qf) {
                        const int q = qf * 16 + lr;
                        pb[qf] = *reinterpret_cast<const short8*>(
                            reinterpret_cast<const char*>(PsW) +
                            q * 128 + ((((kf << 2) + lg) ^ (q & 7)) << 4));
                    }
                    __builtin_amdgcn_s_setprio(1);
#pragma unroll
                    for (int df = 0; df < 4; ++df) {
                        const int d = df * 16 + lr;
                        short8 va = ldsf(Vhs[cur], d, (kf << 2) + lg);
                        short8 vb = ldsf(Vls[cur], d, (kf << 2) + lg);
#pragma unroll
                        for (int qf = 0; qf < 2; ++qf) {
                            yacc[df][qf] = mfma16(va, pb[qf], yacc[df][qf]);
                            yacc[df][qf] = mfma16(vb, pb[qf], yacc[df][qf]);
                        }
                    }
                    __builtin_amdgcn_s_setprio(0);
                }
            }
            cur ^= 1;
        }

#pragma unroll
        for (int qf = 0; qf < 2; ++qf) {
            const float inv = 1.f / lrun[qf];
            const size_t ro = ((size_t)b * TS + (qwbase + qf * 16 + lr)) * D_MODEL + h * DK;
#pragma unroll
            for (int df = 0; df < 4; ++df) {
                ushort4_t oh, ol;
#pragma unroll
                for (int rr = 0; rr < 4; ++rr) {
                    const float v = yacc[df][qf][rr] * inv;
                    oh[rr] = f2bf(v);
                    ol[rr] = f2bf(v - bf2f(oh[rr]));
                }
                *reinterpret_cast<ushort4_t*>(&yh[ro + df * 16 + lg * 4]) = oh;
                *reinterpret_cast<ushort4_t*>(&yl[ro + df * 16 + lg * 4]) = ol;
            }
        }
    }
}

// ---------------------------------------------------------------------------
extern "C" void kernel_launch(void* const* d_in, const int* in_sizes, int n_in,
                              void* d_out, int out_size, void* d_ws, size_t ws_size,
                              hipStream_t stream) {
    const float* x      = (const float*)d_in[0];
    const float* W_qkv  = (const float*)d_in[1];
    const float* b_qkv  = (const float*)d_in[2];
    const float* W_proj = (const float*)d_in[3];
    const float* b_proj = (const float*)d_in[4];
    float* out = (float*)d_out;

    char* ws = (char*)d_ws;
    size_t off = 0;
    auto carve = [&](size_t elems) {
        unsigned short* p = (unsigned short*)(ws + off);
        off += elems * sizeof(unsigned short);
        return p;
    };
    unsigned short* xh   = carve((size_t)M_ROWS * D_MODEL);
    unsigned short* xl   = carve((size_t)M_ROWS * D_MODEL);
    unsigned short* wqh  = carve((size_t)C3 * D_MODEL);
    unsigned short* wql  = carve((size_t)C3 * D_MODEL);
    unsigned short* wph  = carve((size_t)D_MODEL * D_MODEL);
    unsigned short* wpl  = carve((size_t)D_MODEL * D_MODEL);
    unsigned short* qkvh = carve((size_t)M_ROWS * C3);
    unsigned short* qkvl = carve((size_t)M_ROWS * C3);
    unsigned short* vth  = carve((size_t)BS * NH * DK * TS);
    unsigned short* vtl  = carve((size_t)BS * NH * DK * TS);
    unsigned short* yhh  = carve((size_t)M_ROWS * D_MODEL);
    unsigned short* yll  = carve((size_t)M_ROWS * D_MODEL);

    cast_split<<<2048, 256, 0, stream>>>(x, xh, xl, M_ROWS * D_MODEL / 4);
    cast_wT<<<dim3(C3 / 32, D_MODEL / 32), 256, 0, stream>>>(W_qkv, wqh, wql, D_MODEL, C3);
    cast_wT<<<dim3(D_MODEL / 32, D_MODEL / 32), 256, 0, stream>>>(W_proj, wph, wpl, D_MODEL, D_MODEL);

    // qkv = x @ W_qkv + b_qkv   (256 blocks exactly; 3 chained n-tiles each)
    gemm_split2<1, 3><<<256, 512, 0, stream>>>(
        xh, xl, wqh, wql, b_qkv, nullptr, qkvh, qkvl, M_ROWS, C3, D_MODEL);

    v_transpose<<<dim3(TS / 64, BS * NH), 256, 0, stream>>>(qkvh, qkvl, vth, vtl);

    attn_mfma<<<dim3(4, BS * NH), 512, 0, stream>>>(qkvh, vth, vtl, yhh, yll);

    // out = y @ W_proj + b_proj  (256 blocks exactly; 1 tile each)
    gemm_split2<0, 1><<<256, 512, 0, stream>>>(
        yhh, yll, wph, wpl, b_proj, out, nullptr, nullptr, M_ROWS, D_MODEL, D_MODEL);
}